// Round 5
// baseline (736.946 us; speedup 1.0000x reference)
//
#include <hip/hip_runtime.h>
#include <float.h>

// VectorQuantizer: N=262144 rows of D=64 fp32, K=1024 codebook rows.
// out = [x_quantized (N*D f32) | embed_inds (N, written as f32)]
//
// Bit-exact replication of the np reference's fp32 semantics (verified R4):
//   - dot: sequential FMA chain over d, per row
//   - norms: numpy pairwise-8 pattern
//   - s = fadd(xn, es[k]) then fmaf(-2, dot, t1); strict < scan = first-min
//
// R5 perf change: 2 rows per thread -> two INDEPENDENT sequential FMA chains
// interleaved. Per-row rounding order unchanged (bit-exact), but the 4-cyc
// dependent-FMA latency is now hidden within one wave, and each codebook-row
// load feeds 128 FMAs instead of 64.

static constexpr int D_DIM = 64;
static constexpr int K_CB  = 1024;
static constexpr int TPB   = 128;      // threads per block
static constexpr int RPT   = 2;        // rows per thread
static constexpr int RPB   = TPB * RPT;

// numpy pairwise sum, n=64 path: 8 accumulators, sequential adds, fixed tree.
__device__ __forceinline__ float np_sum64_sq(const float* v) {
    float r[8];
#pragma unroll
    for (int j = 0; j < 8; ++j) r[j] = __fmul_rn(v[j], v[j]);
#pragma unroll
    for (int i = 8; i < 64; i += 8)
#pragma unroll
        for (int j = 0; j < 8; ++j) r[j] = __fadd_rn(r[j], __fmul_rn(v[i + j], v[i + j]));
    float t01 = __fadd_rn(r[0], r[1]), t23 = __fadd_rn(r[2], r[3]);
    float t45 = __fadd_rn(r[4], r[5]), t67 = __fadd_rn(r[6], r[7]);
    return __fadd_rn(__fadd_rn(t01, t23), __fadd_rn(t45, t67));
}

__global__ void __launch_bounds__(TPB) vq_kernel(
        const float* __restrict__ x, const float* __restrict__ cb,
        float* __restrict__ out_q, float* __restrict__ out_idx) {
    __shared__ float es[K_CB];     // e_norm (numpy-pattern fp32), 4 KB
    __shared__ int bks[RPB];

    const int tid = threadIdx.x;
    const size_t row0 = (size_t)blockIdx.x * RPB;
    const size_t rowA = row0 + tid;
    const size_t rowB = row0 + TPB + tid;
    const float4* cb4 = reinterpret_cast<const float4*>(cb);

    // --- block-local e_norm[k], numpy pairwise-8 pattern ---
    for (int k = tid; k < K_CB; k += TPB) {
        float cr[D_DIM];
        const float4* c4 = cb4 + k * 16;
#pragma unroll
        for (int c = 0; c < 16; ++c) {
            float4 v = c4[c];
            cr[4 * c + 0] = v.x; cr[4 * c + 1] = v.y;
            cr[4 * c + 2] = v.z; cr[4 * c + 3] = v.w;
        }
        es[k] = np_sum64_sq(cr);
    }
    __syncthreads();

    // --- my two rows -> 128 VGPRs; x_norms numpy-pattern ---
    float xa[D_DIM], xb[D_DIM];
    const float4* ga = reinterpret_cast<const float4*>(x + rowA * D_DIM);
    const float4* gb = reinterpret_cast<const float4*>(x + rowB * D_DIM);
#pragma unroll
    for (int c = 0; c < 16; ++c) {
        float4 v = ga[c];
        xa[4 * c + 0] = v.x; xa[4 * c + 1] = v.y;
        xa[4 * c + 2] = v.z; xa[4 * c + 3] = v.w;
        float4 w = gb[c];
        xb[4 * c + 0] = w.x; xb[4 * c + 1] = w.y;
        xb[4 * c + 2] = w.z; xb[4 * c + 3] = w.w;
    }
    const float xna = np_sum64_sq(xa);
    const float xnb = np_sum64_sq(xb);

    // --- fp32 scan, two independent sequential FMA chains per k ---
    float bA = FLT_MAX, bB = FLT_MAX;
    int kA = 0, kB = 0;
#pragma unroll 2
    for (int k = 0; k < K_CB; ++k) {
        const float4* cr = cb4 + k * 16;   // wave-uniform -> scalar loads
        float da = 0.f, db = 0.f;
#pragma unroll
        for (int c = 0; c < 16; ++c) {
            float4 v = cr[c];
            da = __fmaf_rn(v.x, xa[4 * c + 0], da);
            db = __fmaf_rn(v.x, xb[4 * c + 0], db);
            da = __fmaf_rn(v.y, xa[4 * c + 1], da);
            db = __fmaf_rn(v.y, xb[4 * c + 1], db);
            da = __fmaf_rn(v.z, xa[4 * c + 2], da);
            db = __fmaf_rn(v.z, xb[4 * c + 2], db);
            da = __fmaf_rn(v.w, xa[4 * c + 3], da);
            db = __fmaf_rn(v.w, xb[4 * c + 3], db);
        }
        float en = es[k];
        float sa = __fmaf_rn(-2.0f, da, __fadd_rn(xna, en));
        float sb = __fmaf_rn(-2.0f, db, __fadd_rn(xnb, en));
        if (sa < bA) { bA = sa; kA = k; }
        if (sb < bB) { bB = sb; kB = k; }
    }

    bks[tid]       = kA;
    bks[TPB + tid] = kB;
    __syncthreads();

    // --- coalesced gather-write of x_quantized (256 rows/block) ---
    float4* oq = reinterpret_cast<float4*>(out_q + row0 * D_DIM);
#pragma unroll
    for (int j = 0; j < RPB * 16 / TPB; ++j) {
        int f = tid + TPB * j;
        int r = f >> 4;
        int c = f & 15;
        oq[f] = cb4[(size_t)bks[r] * 16 + c];
    }
    out_idx[rowA] = (float)kA;
    out_idx[rowB] = (float)kB;
}

extern "C" void kernel_launch(void* const* d_in, const int* in_sizes, int n_in,
                              void* d_out, int out_size, void* d_ws, size_t ws_size,
                              hipStream_t stream) {
    const float* x  = (const float*)d_in[0];
    const float* cb = (const float*)d_in[1];
    const int n_rows = in_sizes[0] / D_DIM;     // 262144

    float* out_q   = (float*)d_out;
    float* out_idx = out_q + (size_t)n_rows * D_DIM;

    vq_kernel<<<n_rows / RPB, TPB, 0, stream>>>(x, cb, out_q, out_idx);
}